// Round 2
// baseline (13644.128 us; speedup 1.0000x reference)
//
#include <hip/hip_runtime.h>
#include <stdint.h>

// LSTM: T=1024, B=32, I=512, H=512, fp32.
// Persistent-style kernel, PLAIN launch (cooperative launch failed in R1 —
// returned an error silently; the algorithm never ran).
// Co-residency by capacity: 256 blocks, >=2 blocks/CU of resources on 256 CUs,
// so all blocks are resident; spin-waits cannot deadlock (bounded anyway).
//
// 256 blocks = 4 batch-groups (bg) x 64 j-groups (jg).
// Block (bg,jg) consumes h(t-1) of its 8 batches, produces h(t) for its
// 8 hidden units x 8 batches. Sync domain = 64 blocks sharing bg.
// Weights resident in VGPRs (128 regs); h exchanged through out[] with
// per-(t,bg) release/acquire counters in d_ws. c-state stays block-local.

#define T_STEPS 1024
#define BATCH   32
#define IDIM    512
#define HDIM    512

#define BG      4            // batch groups
#define JG      64           // j groups
#define NBLK    (BG*JG)      // 256 blocks
#define NDOM    JG           // blocks per sync domain (same bg)
#define BPB     (BATCH/BG)   // 8 batches per block
#define JPB     (HDIM/JG)    // 8 hidden units per block
#define RPB     (4*JPB)      // 32 gate rows per block
#define NTHR    256
#define PSTRIDE 257          // padded partials stride (odd -> conflict-free)

__device__ __forceinline__ float sigmoid_f(float v) {
    return 1.0f / (1.0f + __expf(-v));
}
__device__ __forceinline__ float tanh_f(float v) {
    // robust: v->+inf => 1, v->-inf => -1
    float e = __expf(2.0f * v);
    return 1.0f - 2.0f / (e + 1.0f);
}

__global__ __launch_bounds__(NTHR, 1) void lstm_persistent(
    const float* __restrict__ x,     // [T][B][I]
    const float* __restrict__ h0,    // [B][H]
    const float* __restrict__ c0,    // [B][H]
    const float* __restrict__ Wih,   // [4H][I]
    const float* __restrict__ Whh,   // [4H][H]
    const float* __restrict__ bih,   // [4H]
    const float* __restrict__ bhh,   // [4H]
    float* __restrict__ out,         // [T][B][H] ++ h_f[B][H] ++ c_f[B][H]
    unsigned int* cnt)               // [T][BG] arrival counters (zeroed)
{
    __shared__ __align__(16) float tile[BPB * IDIM];   // 16 KB: x or h staging
    __shared__ float part[RPB * PSTRIDE];              // 32.9 KB partial sums
    __shared__ float garr[RPB * 9];                    // gate exchange
    __shared__ float biasl[RPB];

    const int tid = threadIdx.x;
    const int bid = blockIdx.x;
    const int bg  = bid >> 6;        // 0..3
    const int jg  = bid & 63;        // 0..63
    const int ks  = tid >> 3;        // 0..31  k-slice id
    const int rq  = tid & 7;         // 0..7   row-quad id

    // ---- load weight slices into registers (held for all 1024 steps) ----
    // thread owns rows lr = rq*4..rq*4+3; k in {ks*4 + j*128 + 0..3, j=0..3}
    float4 wih[4][4], whh[4][4];
    #pragma unroll
    for (int r = 0; r < 4; ++r) {
        const int lr = rq * 4 + r;                         // 0..31
        const int grow = (lr >> 3) * HDIM + jg * JPB + (lr & 7);  // gate*512 + j
        const float* wi = Wih + (size_t)grow * IDIM;
        const float* wh = Whh + (size_t)grow * HDIM;
        #pragma unroll
        for (int j = 0; j < 4; ++j) {
            const int k = ks * 4 + j * 128;
            wih[r][j] = *(const float4*)(wi + k);
            whh[r][j] = *(const float4*)(wh + k);
        }
    }
    if (tid < RPB) {
        const int grow = (tid >> 3) * HDIM + jg * JPB + (tid & 7);
        biasl[tid] = bih[grow] + bhh[grow];
    }
    const int ab  = tid >> 3;   // activation-thread batch (tid<64)
    const int ajj = tid & 7;    // activation-thread j
    float cstate = 0.0f, hlast = 0.0f;
    if (tid < 64) {
        cstate = c0[(size_t)(bg * BPB + ab) * HDIM + jg * JPB + ajj];
    }
    __syncthreads();

    for (int t = 0; t < T_STEPS; ++t) {
        // ---- 1. stage x[t] tile (independent of h: runs before the wait) ----
        {
            const float* xsrc = x + ((size_t)t * BATCH + bg * BPB) * IDIM;
            #pragma unroll
            for (int i = 0; i < 4; ++i) {
                const int f = tid * 16 + i * 4;
                *(float4*)(tile + f) = *(const float4*)(xsrc + f);
            }
        }
        __syncthreads();

        // ---- 2. x projection into register accumulators ----
        float acc[4][BPB];
        #pragma unroll
        for (int r = 0; r < 4; ++r)
            #pragma unroll
            for (int b = 0; b < BPB; ++b) acc[r][b] = 0.0f;

        #pragma unroll
        for (int j = 0; j < 4; ++j) {
            #pragma unroll
            for (int b = 0; b < BPB; ++b) {
                const float4 v = *(const float4*)(tile + b * IDIM + ks * 4 + j * 128);
                #pragma unroll
                for (int r = 0; r < 4; ++r) {
                    acc[r][b] = fmaf(wih[r][j].x, v.x, acc[r][b]);
                    acc[r][b] = fmaf(wih[r][j].y, v.y, acc[r][b]);
                    acc[r][b] = fmaf(wih[r][j].z, v.z, acc[r][b]);
                    acc[r][b] = fmaf(wih[r][j].w, v.w, acc[r][b]);
                }
            }
        }
        __syncthreads();   // x-tile fully consumed before h overwrites it

        // ---- 3. wait for h(t-1) from the 64 blocks of this batch-group ----
        if (t > 0) {
            if (tid == 0) {
                unsigned int* cp = &cnt[(t - 1) * BG + bg];
                int spins = 0;
                while (__hip_atomic_load(cp, __ATOMIC_RELAXED,
                                         __HIP_MEMORY_SCOPE_AGENT) < (unsigned)NDOM) {
                    __builtin_amdgcn_s_sleep(2);
                    if (++spins > 50000) break;   // bail -> wrong answer, not a hang
                }
                (void)__hip_atomic_load(cp, __ATOMIC_ACQUIRE,
                                        __HIP_MEMORY_SCOPE_AGENT);
            }
            __syncthreads();
        }

        // ---- 4. stage h(t-1) ----
        {
            const float* hsrc = (t == 0)
                ? (h0 + (size_t)bg * BPB * HDIM)
                : (out + ((size_t)(t - 1) * BATCH + bg * BPB) * HDIM);
            #pragma unroll
            for (int i = 0; i < 4; ++i) {
                const int f = tid * 16 + i * 4;
                *(float4*)(tile + f) = *(const float4*)(hsrc + f);
            }
        }
        __syncthreads();

        // ---- 5. h projection ----
        #pragma unroll
        for (int j = 0; j < 4; ++j) {
            #pragma unroll
            for (int b = 0; b < BPB; ++b) {
                const float4 v = *(const float4*)(tile + b * HDIM + ks * 4 + j * 128);
                #pragma unroll
                for (int r = 0; r < 4; ++r) {
                    acc[r][b] = fmaf(whh[r][j].x, v.x, acc[r][b]);
                    acc[r][b] = fmaf(whh[r][j].y, v.y, acc[r][b]);
                    acc[r][b] = fmaf(whh[r][j].z, v.z, acc[r][b]);
                    acc[r][b] = fmaf(whh[r][j].w, v.w, acc[r][b]);
                }
            }
        }

        // ---- 6. spill partials (bank-conflict-free: odd stride) ----
        #pragma unroll
        for (int r = 0; r < 4; ++r) {
            const int lr = rq * 4 + r;
            #pragma unroll
            for (int b = 0; b < BPB; ++b)
                part[lr * PSTRIDE + b * 32 + ks] = acc[r][b];
        }
        __syncthreads();

        // ---- 7. reduce over 32 k-slices: one thread per (row, batch) ----
        {
            const int b  = tid >> 5;    // 0..7
            const int lr = tid & 31;    // 0..31
            const float* p = part + lr * PSTRIDE + b * 32;
            float s0 = 0.f, s1 = 0.f, s2 = 0.f, s3 = 0.f;
            #pragma unroll
            for (int k2 = 0; k2 < 32; k2 += 4) {
                s0 += p[k2]; s1 += p[k2 + 1]; s2 += p[k2 + 2]; s3 += p[k2 + 3];
            }
            garr[lr * 9 + b] = (s0 + s1) + (s2 + s3) + biasl[lr];
        }
        __syncthreads();

        // ---- 8. activations + state update (64 threads own (b,j) cells) ----
        if (tid < 64) {
            const float g_i = garr[(0 * 8 + ajj) * 9 + ab];
            const float g_f = garr[(1 * 8 + ajj) * 9 + ab];
            const float g_g = garr[(2 * 8 + ajj) * 9 + ab];
            const float g_o = garr[(3 * 8 + ajj) * 9 + ab];
            const float ig = sigmoid_f(g_i);
            const float fg = sigmoid_f(g_f);
            const float gg = tanh_f(g_g);
            const float og = sigmoid_f(g_o);
            cstate = fmaf(fg, cstate, ig * gg);
            hlast  = og * tanh_f(cstate);
            out[((size_t)t * BATCH + bg * BPB + ab) * HDIM + jg * JPB + ajj] = hlast;
        }
        __syncthreads();   // drain h writes before the release

        // ---- 9. arrive: release makes h(t) + flag visible device-wide ----
        if (tid == 0) {
            __hip_atomic_fetch_add(&cnt[t * BG + bg], 1u,
                                   __ATOMIC_RELEASE, __HIP_MEMORY_SCOPE_AGENT);
        }
    }

    // ---- final states h_f, c_f ----
    if (tid < 64) {
        const size_t base = (size_t)T_STEPS * BATCH * HDIM;
        const size_t off  = (size_t)(bg * BPB + ab) * HDIM + jg * JPB + ajj;
        out[base + off] = hlast;
        out[base + (size_t)BATCH * HDIM + off] = cstate;
    }
}

extern "C" void kernel_launch(void* const* d_in, const int* in_sizes, int n_in,
                              void* d_out, int out_size, void* d_ws, size_t ws_size,
                              hipStream_t stream) {
    const float* x   = (const float*)d_in[0];
    const float* h0  = (const float*)d_in[1];
    const float* c0  = (const float*)d_in[2];
    const float* Wih = (const float*)d_in[3];
    const float* Whh = (const float*)d_in[4];
    const float* bih = (const float*)d_in[5];
    const float* bhh = (const float*)d_in[6];
    float* out = (float*)d_out;
    unsigned int* cnt = (unsigned int*)d_ws;

    // zero the arrival counters (d_ws is poisoned 0xAA before every launch)
    hipMemsetAsync(cnt, 0, (size_t)T_STEPS * BG * sizeof(unsigned int), stream);

    // Plain launch (graph-capturable, harness-native). Co-residency of all
    // 256 blocks is guaranteed by capacity (>=2 blocks/CU of resources).
    lstm_persistent<<<dim3(NBLK), dim3(NTHR), 0, stream>>>(
        x, h0, c0, Wih, Whh, bih, bhh, out, cnt);
}

// Round 3
// 6100.858 us; speedup vs baseline: 2.2364x; 2.2364x over previous
//
#include <hip/hip_runtime.h>
#include <stdint.h>

// LSTM: T=1024, B=32, I=512, H=512, fp32. Persistent-style, plain launch.
// R3: remove ALL acquire/release cache maintenance from the per-step handoff.
// R2 post-mortem: agent acquire/release => per-step per-block L2 inv/writeback
// (FETCH 543 MB vs 72 MB ideal, 13.3 us/step vs ~1 us of VALU). Now every
// cross-block datum (h, flags) moves via RELAXED agent-scope atomics (sc1,
// straight to the coherence point, no L2 flush); ordering = vmcnt drain in
// __syncthreads before the flag store. Flags are per-producer with magic t+1,
// so no RMW and no zero-init (0xAAAAAAAA poison != any magic). No memset node.
//
// 256 blocks = 4 batch-groups (bg) x 64 j-groups (jg); sync domain = 64
// blocks sharing bg. Weights live in VGPRs for all 1024 steps. c-state block-local.

#define T_STEPS 1024
#define BATCH   32
#define IDIM    512
#define HDIM    512

#define BG      4
#define JG      64
#define NBLK    (BG*JG)
#define BPB     (BATCH/BG)   // 8 batches/block
#define JPB     (HDIM/JG)    // 8 hidden units/block
#define RPB     (4*JPB)      // 32 gate rows/block
#define NTHR    256
#define PSTRIDE 257          // odd stride -> 2-way-max (free) conflicts

__device__ __forceinline__ float sigmoid_f(float v) {
    return 1.0f / (1.0f + __expf(-v));
}
__device__ __forceinline__ float tanh_f(float v) {
    float e = __expf(2.0f * v);
    return 1.0f - 2.0f / (e + 1.0f);
}

__global__ __launch_bounds__(NTHR, 1) void lstm_persistent(
    const float* __restrict__ x,     // [T][B][I]
    const float* __restrict__ h0,    // [B][H]
    const float* __restrict__ c0,    // [B][H]
    const float* __restrict__ Wih,   // [4H][I]
    const float* __restrict__ Whh,   // [4H][H]
    const float* __restrict__ bih,   // [4H]
    const float* __restrict__ bhh,   // [4H]
    float* __restrict__ out,         // [T][B][H] ++ h_f[B][H] ++ c_f[B][H]
    unsigned int* flags)             // [T][BG][JG] magic = t+1 (d_ws, 1 MB)
{
    __shared__ __align__(16) float tile[BPB * IDIM];   // 16 KB x/h staging
    __shared__ float part[RPB * PSTRIDE];              // 32.9 KB partials
    __shared__ float garr[RPB * 9];                    // gate exchange
    __shared__ float biasl[RPB];

    const int tid = threadIdx.x;
    const int bid = blockIdx.x;
    const int bg  = bid >> 6;        // 0..3
    const int jg  = bid & 63;        // 0..63
    const int ks  = tid >> 3;        // 0..31 k-slice
    const int rq  = tid & 7;         // 0..7  row-quad

    // ---- weight slices -> registers (held for all steps) ----
    float4 wih[4][4], whh[4][4];
    #pragma unroll
    for (int r = 0; r < 4; ++r) {
        const int lr = rq * 4 + r;                                // 0..31
        const int grow = (lr >> 3) * HDIM + jg * JPB + (lr & 7);  // gate*512+j
        const float* wi = Wih + (size_t)grow * IDIM;
        const float* wh = Whh + (size_t)grow * HDIM;
        #pragma unroll
        for (int j = 0; j < 4; ++j) {
            const int k = ks * 4 + j * 128;
            wih[r][j] = *(const float4*)(wi + k);
            whh[r][j] = *(const float4*)(wh + k);
        }
    }
    if (tid < RPB) {
        const int grow = (tid >> 3) * HDIM + jg * JPB + (tid & 7);
        biasl[tid] = bih[grow] + bhh[grow];
    }

    // activation threads: 32 threads x 2 adjacent cells (ulong-pair stores)
    const int ab = tid >> 2;          // batch (tid<32)
    const int j0 = (tid & 3) * 2;     // even j within block slice
    float cst0 = 0.f, cst1 = 0.f, hl0 = 0.f, hl1 = 0.f;
    if (tid < 32) {
        const size_t coff = (size_t)(bg * BPB + ab) * HDIM + jg * JPB + j0;
        cst0 = c0[coff];
        cst1 = c0[coff + 1];
    }
    __syncthreads();

    for (int t = 0; t < T_STEPS; ++t) {
        // ---- 1. stage x[t] (conflict-free contiguous lane mapping) ----
        {
            const float* xsrc = x + ((size_t)t * BATCH + bg * BPB) * IDIM;
            #pragma unroll
            for (int i = 0; i < 4; ++i) {
                const int f = i * 1024 + tid * 4;
                *(float4*)(tile + f) = *(const float4*)(xsrc + f);
            }
        }
        __syncthreads();

        // ---- 2. x projection (independent of h: overlaps others' production)
        float acc[4][BPB];
        #pragma unroll
        for (int r = 0; r < 4; ++r)
            #pragma unroll
            for (int b = 0; b < BPB; ++b) acc[r][b] = 0.0f;

        #pragma unroll
        for (int j = 0; j < 4; ++j) {
            #pragma unroll
            for (int b = 0; b < BPB; ++b) {
                const float4 v = *(const float4*)(tile + b * IDIM + ks * 4 + j * 128);
                #pragma unroll
                for (int r = 0; r < 4; ++r) {
                    acc[r][b] = fmaf(wih[r][j].x, v.x, acc[r][b]);
                    acc[r][b] = fmaf(wih[r][j].y, v.y, acc[r][b]);
                    acc[r][b] = fmaf(wih[r][j].z, v.z, acc[r][b]);
                    acc[r][b] = fmaf(wih[r][j].w, v.w, acc[r][b]);
                }
            }
        }

        // ---- 3. wait for the 64 producers of h(t-1) (wave 0 polls; others
        //         park at the barrier; no fences, no L2 maintenance) ----
        if (t > 0) {
            if (tid < 64) {
                unsigned int* fp = &flags[(size_t)(t - 1) * NBLK + bg * JG + tid];
                const unsigned int magic = (unsigned int)t;   // (t-1)+1
                int spins = 0;
                while (__hip_atomic_load(fp, __ATOMIC_RELAXED,
                                         __HIP_MEMORY_SCOPE_AGENT) != magic) {
                    __builtin_amdgcn_s_sleep(1);
                    if (++spins > 30000) break;   // bail -> visible error, not hang
                }
            }
        }
        __syncthreads();   // also isolates x-tile reads from h-tile writes

        // ---- 4. stage h(t-1): relaxed agent atomics (L3 path, no staleness)
        if (t == 0) {
            const float* hsrc = h0 + (size_t)bg * BPB * HDIM;
            #pragma unroll
            for (int i = 0; i < 4; ++i) {
                const int f = i * 1024 + tid * 4;
                *(float4*)(tile + f) = *(const float4*)(hsrc + f);
            }
        } else {
            unsigned long long* hsrc = (unsigned long long*)
                (out + ((size_t)(t - 1) * BATCH + bg * BPB) * HDIM);
            unsigned long long* tq = (unsigned long long*)tile;
            #pragma unroll
            for (int i = 0; i < 8; ++i) {
                const int idx = i * 256 + tid;      // 2048 ulongs = 16 KB
                tq[idx] = __hip_atomic_load(&hsrc[idx], __ATOMIC_RELAXED,
                                            __HIP_MEMORY_SCOPE_AGENT);
            }
        }
        __syncthreads();

        // ---- 5. h projection ----
        #pragma unroll
        for (int j = 0; j < 4; ++j) {
            #pragma unroll
            for (int b = 0; b < BPB; ++b) {
                const float4 v = *(const float4*)(tile + b * HDIM + ks * 4 + j * 128);
                #pragma unroll
                for (int r = 0; r < 4; ++r) {
                    acc[r][b] = fmaf(whh[r][j].x, v.x, acc[r][b]);
                    acc[r][b] = fmaf(whh[r][j].y, v.y, acc[r][b]);
                    acc[r][b] = fmaf(whh[r][j].z, v.z, acc[r][b]);
                    acc[r][b] = fmaf(whh[r][j].w, v.w, acc[r][b]);
                }
            }
        }

        // ---- 6. spill partials (2-way max -> free) ----
        #pragma unroll
        for (int r = 0; r < 4; ++r) {
            const int lr = rq * 4 + r;
            #pragma unroll
            for (int b = 0; b < BPB; ++b)
                part[lr * PSTRIDE + b * 32 + ks] = acc[r][b];
        }
        __syncthreads();

        // ---- 7. reduce 32 k-slices ----
        {
            const int b  = tid >> 5;
            const int lr = tid & 31;
            const float* p = part + lr * PSTRIDE + b * 32;
            float s0 = 0.f, s1 = 0.f, s2 = 0.f, s3 = 0.f;
            #pragma unroll
            for (int k2 = 0; k2 < 32; k2 += 4) {
                s0 += p[k2]; s1 += p[k2 + 1]; s2 += p[k2 + 2]; s3 += p[k2 + 3];
            }
            garr[lr * 9 + b] = (s0 + s1) + (s2 + s3) + biasl[lr];
        }
        __syncthreads();

        // ---- 8. activations, state update, packed h store (32 threads) ----
        if (tid < 32) {
            const float i0 = sigmoid_f(garr[(0 * 8 + j0    ) * 9 + ab]);
            const float f0 = sigmoid_f(garr[(1 * 8 + j0    ) * 9 + ab]);
            const float g0 = tanh_f  (garr[(2 * 8 + j0    ) * 9 + ab]);
            const float o0 = sigmoid_f(garr[(3 * 8 + j0    ) * 9 + ab]);
            const float i1 = sigmoid_f(garr[(0 * 8 + j0 + 1) * 9 + ab]);
            const float f1 = sigmoid_f(garr[(1 * 8 + j0 + 1) * 9 + ab]);
            const float g1 = tanh_f  (garr[(2 * 8 + j0 + 1) * 9 + ab]);
            const float o1 = sigmoid_f(garr[(3 * 8 + j0 + 1) * 9 + ab]);
            cst0 = fmaf(f0, cst0, i0 * g0);
            cst1 = fmaf(f1, cst1, i1 * g1);
            hl0  = o0 * tanh_f(cst0);
            hl1  = o1 * tanh_f(cst1);
            union { float f[2]; unsigned long long q; } u;
            u.f[0] = hl0; u.f[1] = hl1;
            const size_t e = ((size_t)t * BATCH + bg * BPB + ab) * HDIM
                           + jg * JPB + j0;
            __hip_atomic_store((unsigned long long*)(out + e), u.q,
                               __ATOMIC_RELAXED, __HIP_MEMORY_SCOPE_AGENT);
        }
        __syncthreads();   // s_waitcnt vmcnt(0) here orders h-stores < flag

        // ---- 9. publish: relaxed flag store (no fence, no L2 flush) ----
        if (tid == 0) {
            __hip_atomic_store(&flags[(size_t)t * NBLK + bg * JG + jg],
                               (unsigned int)(t + 1),
                               __ATOMIC_RELAXED, __HIP_MEMORY_SCOPE_AGENT);
        }
    }

    // ---- final states h_f, c_f ----
    if (tid < 32) {
        const size_t base = (size_t)T_STEPS * BATCH * HDIM;
        const size_t off  = (size_t)(bg * BPB + ab) * HDIM + jg * JPB + j0;
        out[base + off]     = hl0;
        out[base + off + 1] = hl1;
        out[base + (size_t)BATCH * HDIM + off]     = cst0;
        out[base + (size_t)BATCH * HDIM + off + 1] = cst1;
    }
}

extern "C" void kernel_launch(void* const* d_in, const int* in_sizes, int n_in,
                              void* d_out, int out_size, void* d_ws, size_t ws_size,
                              hipStream_t stream) {
    const float* x   = (const float*)d_in[0];
    const float* h0  = (const float*)d_in[1];
    const float* c0  = (const float*)d_in[2];
    const float* Wih = (const float*)d_in[3];
    const float* Whh = (const float*)d_in[4];
    const float* bih = (const float*)d_in[5];
    const float* bhh = (const float*)d_in[6];
    float* out = (float*)d_out;
    unsigned int* flags = (unsigned int*)d_ws;   // 1 MB; poison 0xAAAAAAAA != magic,
                                                 // so no zeroing needed.

    lstm_persistent<<<dim3(NBLK), dim3(NTHR), 0, stream>>>(
        x, h0, c0, Wih, Whh, bih, bhh, out, flags);
}

// Round 4
// 4926.044 us; speedup vs baseline: 2.7698x; 1.2385x over previous
//
#include <hip/hip_runtime.h>
#include <stdint.h>

// LSTM: T=1024, B=32, I=512, H=512, fp32. Persistent-style, plain launch.
// R4: fuse h-data + validity flag into single 64-bit ring words
// ((fp32_bits<<32)|tag). One relaxed agent-scope store publishes a value;
// the consumer's poll IS the data load -> 1 L3 round trip on the serial
// chain instead of 3 (R3: store-drain + flag RT + poll RT + data RT).
// Consumers prefetch their 16 ring words BEFORE the x-projection so the RT
// hides under ~2k cycles of independent FMA work.
// Ring depth 4, slot = t&3: safe by induction (writer at step t has consumed
// h(t-1) => all peers finished step t-1 => all are past reading slot (t-4)).
// Poison 0xAAAAAAAA != any tag (1..1024) -> no init needed, no memset node.
//
// 256 blocks = 4 batch-groups (bg) x 64 j-groups (jg). Weights in VGPRs for
// all 1024 steps. c-state block-local. out[] gets plain fp32 stores only.

#define T_STEPS 1024
#define BATCH   32
#define IDIM    512
#define HDIM    512

#define BG      4
#define JG      64
#define NBLK    (BG*JG)
#define BPB     (BATCH/BG)   // 8 batches/block
#define JPB     (HDIM/JG)    // 8 hidden units/block
#define RPB     (4*JPB)      // 32 gate rows/block
#define NTHR    256
#define PSTRIDE 257          // odd stride -> worst 2-way (free) LDS conflicts
#define RING_D  4
#define HWORDS  (BPB*HDIM)   // 4096 tagged words per (slot,bg)
#define WPT     (HWORDS/NTHR) // 16 words per consumer thread

__device__ __forceinline__ float sigmoid_f(float v) {
    return 1.0f / (1.0f + __expf(-v));
}
__device__ __forceinline__ float tanh_f(float v) {
    float e = __expf(2.0f * v);
    return 1.0f - 2.0f / (e + 1.0f);
}

__global__ __launch_bounds__(NTHR, 1) void lstm_persistent(
    const float* __restrict__ x,     // [T][B][I]
    const float* __restrict__ h0,    // [B][H]
    const float* __restrict__ c0,    // [B][H]
    const float* __restrict__ Wih,   // [4H][I]
    const float* __restrict__ Whh,   // [4H][H]
    const float* __restrict__ bih,   // [4H]
    const float* __restrict__ bhh,   // [4H]
    float* __restrict__ out,         // [T][B][H] ++ h_f[B][H] ++ c_f[B][H]
    unsigned long long* __restrict__ ring)  // [4][BG][HWORDS] tagged words
{
    __shared__ __align__(16) float xtile[BPB * IDIM];   // 16 KB
    __shared__ __align__(16) float htile[BPB * HDIM];   // 16 KB
    __shared__ float part[RPB * PSTRIDE];               // 32.9 KB
    __shared__ float garr[RPB * 9];
    __shared__ float biasl[RPB];

    const int tid = threadIdx.x;
    const int bid = blockIdx.x;
    const int bg  = bid >> 6;        // 0..3
    const int jg  = bid & 63;        // 0..63
    const int ks  = tid >> 3;        // 0..31 k-slice
    const int rq  = tid & 7;         // 0..7  row-quad

    // ---- weight slices -> registers (held for all steps) ----
    float4 wih[4][4], whh[4][4];
    #pragma unroll
    for (int r = 0; r < 4; ++r) {
        const int lr = rq * 4 + r;                                // 0..31
        const int grow = (lr >> 3) * HDIM + jg * JPB + (lr & 7);  // gate*512+j
        const float* wi = Wih + (size_t)grow * IDIM;
        const float* wh = Whh + (size_t)grow * HDIM;
        #pragma unroll
        for (int j = 0; j < 4; ++j) {
            const int k = ks * 4 + j * 128;
            wih[r][j] = *(const float4*)(wi + k);
            whh[r][j] = *(const float4*)(wh + k);
        }
    }
    if (tid < RPB) {
        const int grow = (tid >> 3) * HDIM + jg * JPB + (tid & 7);
        biasl[tid] = bih[grow] + bhh[grow];
    }

    // activation threads: 32 threads x 2 adjacent cells
    const int ab = tid >> 2;          // batch (tid<32)
    const int j0 = (tid & 3) * 2;     // even j within block slice
    float cst0 = 0.f, cst1 = 0.f, hl0 = 0.f, hl1 = 0.f;
    if (tid < 32) {
        const size_t coff = (size_t)(bg * BPB + ab) * HDIM + jg * JPB + j0;
        cst0 = c0[coff];
        cst1 = c0[coff + 1];
    }
    __syncthreads();

    for (int t = 0; t < T_STEPS; ++t) {
        // ---- 1. stage x[t] (contiguous lane mapping, conflict-free) ----
        {
            const float* xsrc = x + ((size_t)t * BATCH + bg * BPB) * IDIM;
            #pragma unroll
            for (int i = 0; i < 4; ++i) {
                const int f = i * 1024 + tid * 4;
                *(float4*)(xtile + f) = *(const float4*)(xsrc + f);
            }
        }
        __syncthreads();   // A: xtile ready; also orders garr/part reuse

        // ---- 2. prefetch tagged h(t-1) words (RT hides under x-proj) ----
        unsigned long long v[WPT];
        const unsigned int tag = (unsigned int)t;   // producers wrote (t-1)+1
        const unsigned long long* rb =
            ring + ((size_t)((t - 1) & 3) * BG + bg) * HWORDS;
        if (t > 0) {
            #pragma unroll
            for (int w = 0; w < WPT; ++w)
                v[w] = __hip_atomic_load(rb + w * NTHR + tid,
                                         __ATOMIC_RELAXED,
                                         __HIP_MEMORY_SCOPE_AGENT);
        }

        // ---- 3. x projection ----
        float acc[4][BPB];
        #pragma unroll
        for (int r = 0; r < 4; ++r)
            #pragma unroll
            for (int b = 0; b < BPB; ++b) acc[r][b] = 0.0f;

        #pragma unroll
        for (int j = 0; j < 4; ++j) {
            #pragma unroll
            for (int b = 0; b < BPB; ++b) {
                const float4 vx = *(const float4*)(xtile + b * IDIM + ks * 4 + j * 128);
                #pragma unroll
                for (int r = 0; r < 4; ++r) {
                    acc[r][b] = fmaf(wih[r][j].x, vx.x, acc[r][b]);
                    acc[r][b] = fmaf(wih[r][j].y, vx.y, acc[r][b]);
                    acc[r][b] = fmaf(wih[r][j].z, vx.z, acc[r][b]);
                    acc[r][b] = fmaf(wih[r][j].w, vx.w, acc[r][b]);
                }
            }
        }

        // ---- 4. validate tags; reload stragglers; write h into htile ----
        if (t > 0) {
            for (int sweep = 0; sweep < 30000; ++sweep) {
                bool ok = true;
                #pragma unroll
                for (int w = 0; w < WPT; ++w) {
                    if ((unsigned int)v[w] != tag) {
                        v[w] = __hip_atomic_load(rb + w * NTHR + tid,
                                                 __ATOMIC_RELAXED,
                                                 __HIP_MEMORY_SCOPE_AGENT);
                        ok = false;
                    }
                }
                if (ok) break;                     // bail path -> visible error
                __builtin_amdgcn_s_sleep(1);
            }
            #pragma unroll
            for (int w = 0; w < WPT; ++w)
                htile[w * NTHR + tid] =
                    __uint_as_float((unsigned int)(v[w] >> 32));
        } else {
            const float* hsrc = h0 + (size_t)bg * BPB * HDIM;
            #pragma unroll
            for (int i = 0; i < 4; ++i) {
                const int f = i * 1024 + tid * 4;
                *(float4*)(htile + f) = *(const float4*)(hsrc + f);
            }
        }
        __syncthreads();   // D: htile ready

        // ---- 5. h projection ----
        #pragma unroll
        for (int j = 0; j < 4; ++j) {
            #pragma unroll
            for (int b = 0; b < BPB; ++b) {
                const float4 vh = *(const float4*)(htile + b * HDIM + ks * 4 + j * 128);
                #pragma unroll
                for (int r = 0; r < 4; ++r) {
                    acc[r][b] = fmaf(whh[r][j].x, vh.x, acc[r][b]);
                    acc[r][b] = fmaf(whh[r][j].y, vh.y, acc[r][b]);
                    acc[r][b] = fmaf(whh[r][j].z, vh.z, acc[r][b]);
                    acc[r][b] = fmaf(whh[r][j].w, vh.w, acc[r][b]);
                }
            }
        }

        // ---- 6. spill partials ----
        #pragma unroll
        for (int r = 0; r < 4; ++r) {
            const int lr = rq * 4 + r;
            #pragma unroll
            for (int b = 0; b < BPB; ++b)
                part[lr * PSTRIDE + b * 32 + ks] = acc[r][b];
        }
        __syncthreads();   // E

        // ---- 7. reduce 32 k-slices ----
        {
            const int b  = tid >> 5;
            const int lr = tid & 31;
            const float* p = part + lr * PSTRIDE + b * 32;
            float s0 = 0.f, s1 = 0.f, s2 = 0.f, s3 = 0.f;
            #pragma unroll
            for (int k2 = 0; k2 < 32; k2 += 4) {
                s0 += p[k2]; s1 += p[k2 + 1]; s2 += p[k2 + 2]; s3 += p[k2 + 3];
            }
            garr[lr * 9 + b] = (s0 + s1) + (s2 + s3) + biasl[lr];
        }
        __syncthreads();   // F

        // ---- 8. activations, state update, publish (32 threads) ----
        if (tid < 32) {
            const float i0 = sigmoid_f(garr[(0 * 8 + j0    ) * 9 + ab]);
            const float f0 = sigmoid_f(garr[(1 * 8 + j0    ) * 9 + ab]);
            const float g0 = tanh_f  (garr[(2 * 8 + j0    ) * 9 + ab]);
            const float o0 = sigmoid_f(garr[(3 * 8 + j0    ) * 9 + ab]);
            const float i1 = sigmoid_f(garr[(0 * 8 + j0 + 1) * 9 + ab]);
            const float f1 = sigmoid_f(garr[(1 * 8 + j0 + 1) * 9 + ab]);
            const float g1 = tanh_f  (garr[(2 * 8 + j0 + 1) * 9 + ab]);
            const float o1 = sigmoid_f(garr[(3 * 8 + j0 + 1) * 9 + ab]);
            cst0 = fmaf(f0, cst0, i0 * g0);
            cst1 = fmaf(f1, cst1, i1 * g1);
            hl0  = o0 * tanh_f(cst0);
            hl1  = o1 * tanh_f(cst1);

            // output store (plain; nobody reads out[] during the run)
            union { float f[2]; unsigned long long q; } u;
            u.f[0] = hl0; u.f[1] = hl1;
            *(unsigned long long*)(out + ((size_t)t * BATCH + bg * BPB + ab) * HDIM
                                       + jg * JPB + j0) = u.q;

            // tagged ring publish: data+flag in one word, no drain needed
            const unsigned long long tg = (unsigned long long)(t + 1);
            unsigned long long* rw = ring
                + ((size_t)(t & 3) * BG + bg) * HWORDS
                + ab * HDIM + jg * JPB + j0;
            __hip_atomic_store(rw,
                (((unsigned long long)__float_as_uint(hl0)) << 32) | tg,
                __ATOMIC_RELAXED, __HIP_MEMORY_SCOPE_AGENT);
            __hip_atomic_store(rw + 1,
                (((unsigned long long)__float_as_uint(hl1)) << 32) | tg,
                __ATOMIC_RELAXED, __HIP_MEMORY_SCOPE_AGENT);
        }
        // no barrier here: A/D/E/F already separate all cross-step hazards
    }

    // ---- final states h_f, c_f ----
    if (tid < 32) {
        const size_t base = (size_t)T_STEPS * BATCH * HDIM;
        const size_t off  = (size_t)(bg * BPB + ab) * HDIM + jg * JPB + j0;
        out[base + off]     = hl0;
        out[base + off + 1] = hl1;
        out[base + (size_t)BATCH * HDIM + off]     = cst0;
        out[base + (size_t)BATCH * HDIM + off + 1] = cst1;
    }
}

extern "C" void kernel_launch(void* const* d_in, const int* in_sizes, int n_in,
                              void* d_out, int out_size, void* d_ws, size_t ws_size,
                              hipStream_t stream) {
    const float* x   = (const float*)d_in[0];
    const float* h0  = (const float*)d_in[1];
    const float* c0  = (const float*)d_in[2];
    const float* Wih = (const float*)d_in[3];
    const float* Whh = (const float*)d_in[4];
    const float* bih = (const float*)d_in[5];
    const float* bhh = (const float*)d_in[6];
    float* out = (float*)d_out;
    unsigned long long* ring = (unsigned long long*)d_ws;  // 512 KB; 0xAA poison
                                                           // != any tag -> no init
    lstm_persistent<<<dim3(NBLK), dim3(NTHR), 0, stream>>>(
        x, h0, c0, Wih, Whh, bih, bhh, out, ring);
}